// Round 1
// baseline (128.683 us; speedup 1.0000x reference)
//
#include <hip/hip_runtime.h>
#include <math.h>

#define E_DIM 1024
#define H_DIM 2048
#define R_DIM 1024
#define RULES 50000

// d_out layout: [out 50000][h 2048][c 2048][remainder_out 1024]
#define OUT_H  50000
#define OUT_C  52048
#define OUT_RO 54096

// ws layout (float offsets); all blocks write disjoint fixed slots -> deterministic
#define WS_XP    0          // [8][1024]   x partials
#define WS_X     8192       // [1024]      final x
#define WS_H     9216       // [2048]      h (also written to d_out)
#define WS_PL    11264      // [8][50000]  logits partials
#define WS_LOG   411264     // [50000]     relu'd logits
#define WS_BSUM  461264     // [49]        per-block sum(exp(logit))
#define WS_PRO   461320     // [16][1024]  remainder_out partials
// total ~478k floats ~1.9 MB

__device__ __forceinline__ float sigf(float x) { return 1.f / (1.f + expf(-x)); }

// ---- x = emb[ident] + relu(rem @ W_rin + b_rin) ----------------------------
__global__ __launch_bounds__(256) void k_x_partial(const float* __restrict__ rem,
    const float* __restrict__ W_rin, float* __restrict__ xp)
{
    __shared__ float rs[128];
    int ec = blockIdx.x, rc = blockIdx.y;
    if (threadIdx.x < 128) rs[threadIdx.x] = rem[rc * 128 + threadIdx.x];
    __syncthreads();
    int e = ec * 256 + threadIdx.x;
    const float* base = W_rin + (size_t)rc * 128 * E_DIM + e;
    float acc = 0.f;
#pragma unroll 8
    for (int rr = 0; rr < 128; ++rr)
        acc = fmaf(rs[rr], base[(size_t)rr * E_DIM], acc);
    xp[rc * E_DIM + e] = acc;
}

__global__ __launch_bounds__(256) void k_x_final(const float* __restrict__ xp,
    const float* __restrict__ b_rin, const float* __restrict__ emb,
    const int* __restrict__ ident, float* __restrict__ x)
{
    int e = blockIdx.x * 256 + threadIdx.x;
    float s = 0.f;
#pragma unroll
    for (int rc = 0; rc < 8; ++rc) s += xp[rc * E_DIM + e];
    long long row = (long long)ident[0] * E_DIM;
    x[e] = emb[row + e] + fmaxf(s + b_rin[e], 0.f);
}

// ---- LSTM cell: one block per hidden index k; 4 waves = gates i,f,g,o ------
__global__ __launch_bounds__(256) void k_lstm(const float* __restrict__ x,
    const float* __restrict__ h0, const float* __restrict__ c0,
    const float* __restrict__ W_ih, const float* __restrict__ W_hh,
    const float* __restrict__ b_ih, const float* __restrict__ b_hh,
    float* __restrict__ d_out, float* __restrict__ ws_h)
{
    int k = blockIdx.x;
    int w = threadIdx.x >> 6, lane = threadIdx.x & 63;
    int j = w * H_DIM + k;   // torch gate order i,f,g,o == split order
    const float4* Wi = (const float4*)(W_ih + (size_t)j * E_DIM);
    const float4* Wh = (const float4*)(W_hh + (size_t)j * H_DIM);
    const float4* x4 = (const float4*)x;
    const float4* h4 = (const float4*)h0;
    float acc = 0.f;
#pragma unroll
    for (int s = 0; s < 4; ++s) {              // E_DIM/4 = 256 float4, 64 lanes
        int idx = s * 64 + lane;
        float4 wv = Wi[idx], xv = x4[idx];
        acc += wv.x * xv.x + wv.y * xv.y + wv.z * xv.z + wv.w * xv.w;
    }
#pragma unroll
    for (int s = 0; s < 8; ++s) {              // H_DIM/4 = 512 float4
        int idx = s * 64 + lane;
        float4 wv = Wh[idx], hv = h4[idx];
        acc += wv.x * hv.x + wv.y * hv.y + wv.z * hv.z + wv.w * hv.w;
    }
#pragma unroll
    for (int off = 32; off > 0; off >>= 1) acc += __shfl_xor(acc, off);
    __shared__ float gl[4];
    if (lane == 0) gl[w] = acc + b_ih[j] + b_hh[j];
    __syncthreads();
    if (threadIdx.x == 0) {
        float gi = gl[0], gf = gl[1], gg = gl[2], go = gl[3];
        float c = sigf(gf) * c0[k] + sigf(gi) * tanhf(gg);
        float h = sigf(go) * tanhf(c);
        d_out[OUT_H + k] = h;
        d_out[OUT_C + k] = c;
        ws_h[k] = h;
    }
}

// ---- logits partial: grid(49 j-blocks, 8 h-chunks), thread = 4 columns -----
__global__ __launch_bounds__(256) void k_logits_partial(const float* __restrict__ h,
    const float* __restrict__ W_out, float* __restrict__ pl)
{
    __shared__ float hs[256];
    int hc = blockIdx.y;
    hs[threadIdx.x] = h[hc * 256 + threadIdx.x];
    __syncthreads();
    int j0 = blockIdx.x * 1024 + threadIdx.x * 4;
    if (j0 >= RULES) return;
    float4 acc = {0.f, 0.f, 0.f, 0.f};
    const float* base = W_out + (size_t)hc * 256 * RULES + j0;
#pragma unroll 8
    for (int hh = 0; hh < 256; ++hh) {
        float hv = hs[hh];
        float4 wv = *(const float4*)(base + (size_t)hh * RULES);
        acc.x = fmaf(hv, wv.x, acc.x);
        acc.y = fmaf(hv, wv.y, acc.y);
        acc.z = fmaf(hv, wv.z, acc.z);
        acc.w = fmaf(hv, wv.w, acc.w);
    }
    *(float4*)(pl + (size_t)hc * RULES + j0) = acc;
}

// ---- remainder_out partial: 16 h-chunks of 128 -----------------------------
__global__ __launch_bounds__(256) void k_ro_partial(const float* __restrict__ h,
    const float* __restrict__ W_ro, float* __restrict__ pro)
{
    __shared__ float hs[128];
    int hc = blockIdx.x;
    if (threadIdx.x < 128) hs[threadIdx.x] = h[hc * 128 + threadIdx.x];
    __syncthreads();
    int j0 = threadIdx.x * 4;
    float4 acc = {0.f, 0.f, 0.f, 0.f};
    const float* base = W_ro + (size_t)hc * 128 * R_DIM + j0;
#pragma unroll 8
    for (int hh = 0; hh < 128; ++hh) {
        float hv = hs[hh];
        float4 wv = *(const float4*)(base + (size_t)hh * R_DIM);
        acc.x = fmaf(hv, wv.x, acc.x);
        acc.y = fmaf(hv, wv.y, acc.y);
        acc.z = fmaf(hv, wv.z, acc.z);
        acc.w = fmaf(hv, wv.w, acc.w);
    }
    *(float4*)(pro + hc * R_DIM + j0) = acc;
}

// ---- finalize logits: sum 8 partials, +bias, relu, block sum(exp) ----------
__global__ __launch_bounds__(256) void k_logit_final(const float* __restrict__ pl,
    const float* __restrict__ b_out, float* __restrict__ logits,
    float* __restrict__ bsum)
{
    int j0 = blockIdx.x * 1024 + threadIdx.x * 4;
    float se = 0.f;
    if (j0 < RULES) {
        float4 s = {0.f, 0.f, 0.f, 0.f};
#pragma unroll
        for (int hc = 0; hc < 8; ++hc) {
            float4 p = *(const float4*)(pl + (size_t)hc * RULES + j0);
            s.x += p.x; s.y += p.y; s.z += p.z; s.w += p.w;
        }
        float4 b = *(const float4*)(b_out + j0);
        float4 l;
        l.x = fmaxf(s.x + b.x, 0.f);
        l.y = fmaxf(s.y + b.y, 0.f);
        l.z = fmaxf(s.z + b.z, 0.f);
        l.w = fmaxf(s.w + b.w, 0.f);
        *(float4*)(logits + j0) = l;
        se = expf(l.x) + expf(l.y) + expf(l.z) + expf(l.w);
    }
    __shared__ float red[256];
    red[threadIdx.x] = se;
    __syncthreads();
    for (int off = 128; off > 0; off >>= 1) {
        if (threadIdx.x < off) red[threadIdx.x] += red[threadIdx.x + off];
        __syncthreads();
    }
    if (threadIdx.x == 0) bsum[blockIdx.x] = red[0];
}

// ---- finalize remainder_out ------------------------------------------------
__global__ __launch_bounds__(256) void k_ro_final(const float* __restrict__ pro,
    const float* __restrict__ b_ro, float* __restrict__ out_ro)
{
    int j0 = threadIdx.x * 4;
    float4 s = {0.f, 0.f, 0.f, 0.f};
#pragma unroll
    for (int hc = 0; hc < 16; ++hc) {
        float4 p = *(const float4*)(pro + hc * R_DIM + j0);
        s.x += p.x; s.y += p.y; s.z += p.z; s.w += p.w;
    }
    float4 b = *(const float4*)(b_ro + j0);
    float4 o;
    o.x = fmaxf(s.x + b.x, 0.f);
    o.y = fmaxf(s.y + b.y, 0.f);
    o.z = fmaxf(s.z + b.z, 0.f);
    o.w = fmaxf(s.w + b.w, 0.f);
    *(float4*)(out_ro + j0) = o;
}

// ---- out = logits - log(sum(exp)) ------------------------------------------
__global__ __launch_bounds__(256) void k_out(const float* __restrict__ logits,
    const float* __restrict__ bsum, float* __restrict__ d_out)
{
    __shared__ float lse_s;
    if (threadIdx.x == 0) {
        float s = 0.f;
        for (int i = 0; i < 49; ++i) s += bsum[i];   // fixed order: deterministic
        lse_s = logf(s);
    }
    __syncthreads();
    int j = blockIdx.x * 256 + threadIdx.x;
    if (j < RULES) d_out[j] = logits[j] - lse_s;
}

extern "C" void kernel_launch(void* const* d_in, const int* in_sizes, int n_in,
                              void* d_out, int out_size, void* d_ws, size_t ws_size,
                              hipStream_t stream)
{
    const int*   ident = (const int*)  d_in[0];
    const float* rem   = (const float*)d_in[1];
    const float* h0    = (const float*)d_in[2];
    const float* c0    = (const float*)d_in[3];
    const float* emb   = (const float*)d_in[4];
    const float* W_rin = (const float*)d_in[5];
    const float* b_rin = (const float*)d_in[6];
    const float* W_ih  = (const float*)d_in[7];
    const float* W_hh  = (const float*)d_in[8];
    const float* b_ih  = (const float*)d_in[9];
    const float* b_hh  = (const float*)d_in[10];
    const float* W_ro  = (const float*)d_in[11];
    const float* b_ro  = (const float*)d_in[12];
    const float* W_out = (const float*)d_in[13];
    const float* b_out = (const float*)d_in[14];
    float* out = (float*)d_out;
    float* ws  = (float*)d_ws;

    k_x_partial<<<dim3(4, 8), 256, 0, stream>>>(rem, W_rin, ws + WS_XP);
    k_x_final<<<4, 256, 0, stream>>>(ws + WS_XP, b_rin, emb, ident, ws + WS_X);
    k_lstm<<<2048, 256, 0, stream>>>(ws + WS_X, h0, c0, W_ih, W_hh, b_ih, b_hh,
                                     out, ws + WS_H);
    k_logits_partial<<<dim3(49, 8), 256, 0, stream>>>(ws + WS_H, W_out, ws + WS_PL);
    k_ro_partial<<<16, 256, 0, stream>>>(ws + WS_H, W_ro, ws + WS_PRO);
    k_logit_final<<<49, 256, 0, stream>>>(ws + WS_PL, b_out, ws + WS_LOG, ws + WS_BSUM);
    k_ro_final<<<1, 256, 0, stream>>>(ws + WS_PRO, b_ro, out + OUT_RO);
    k_out<<<196, 256, 0, stream>>>(ws + WS_LOG, ws + WS_BSUM, out);
}

// Round 2
// 123.109 us; speedup vs baseline: 1.0453x; 1.0453x over previous
//
#include <hip/hip_runtime.h>
#include <math.h>

#define E_DIM 1024
#define H_DIM 2048
#define R_DIM 1024
#define RULES 50000

// d_out layout: [out 50000][h 2048][c 2048][remainder_out 1024]
#define OUT_H  50000
#define OUT_C  52048
#define OUT_RO 54096

// ws layout (float offsets); all blocks write disjoint fixed slots -> deterministic
#define WS_XP    0          // [8][1024]    x partials (rem @ W_rin)
#define WS_H     8192       // [2048]       h
#define WS_PL    10240      // [16][50000]  logits partials
#define WS_LOG   810240     // [50000]      relu'd logits
#define WS_BSUM  860240     // [49]         per-block sum(exp(logit))
#define WS_PRO   860292     // [16][1024]   remainder_out partials
// total ~877k floats ~3.5 MB

__device__ __forceinline__ float sigf(float x) { return 1.f / (1.f + expf(-x)); }

// ---- xp[rc][e] = partial of rem @ W_rin ------------------------------------
__global__ __launch_bounds__(256) void k_x_partial(const float* __restrict__ rem,
    const float* __restrict__ W_rin, float* __restrict__ xp)
{
    __shared__ float rs[128];
    int ec = blockIdx.x, rc = blockIdx.y;
    if (threadIdx.x < 128) rs[threadIdx.x] = rem[rc * 128 + threadIdx.x];
    __syncthreads();
    int e = ec * 256 + threadIdx.x;
    const float* base = W_rin + (size_t)rc * 128 * E_DIM + e;
    float acc = 0.f;
#pragma unroll 8
    for (int rr = 0; rr < 128; ++rr)
        acc = fmaf(rs[rr], base[(size_t)rr * E_DIM], acc);
    xp[rc * E_DIM + e] = acc;
}

// ---- LSTM cell; rebuilds x per block from xp (L2-resident) -----------------
__global__ __launch_bounds__(256) void k_lstm(const float* __restrict__ xp,
    const float* __restrict__ b_rin, const float* __restrict__ emb,
    const int* __restrict__ ident,
    const float* __restrict__ h0, const float* __restrict__ c0,
    const float* __restrict__ W_ih, const float* __restrict__ W_hh,
    const float* __restrict__ b_ih, const float* __restrict__ b_hh,
    float* __restrict__ d_out, float* __restrict__ ws_h)
{
    __shared__ float xs[E_DIM];
    long long row = (long long)ident[0] * E_DIM;
#pragma unroll
    for (int e = threadIdx.x; e < E_DIM; e += 256) {
        float s = 0.f;
#pragma unroll
        for (int rc = 0; rc < 8; ++rc) s += xp[rc * E_DIM + e];
        xs[e] = emb[row + e] + fmaxf(s + b_rin[e], 0.f);
    }
    __syncthreads();

    int k = blockIdx.x;
    int w = threadIdx.x >> 6, lane = threadIdx.x & 63;
    int j = w * H_DIM + k;   // torch gate order i,f,g,o == split order
    const float4* Wi = (const float4*)(W_ih + (size_t)j * E_DIM);
    const float4* Wh = (const float4*)(W_hh + (size_t)j * H_DIM);
    const float4* x4 = (const float4*)xs;
    const float4* h4 = (const float4*)h0;
    float acc = 0.f;
#pragma unroll
    for (int s = 0; s < 4; ++s) {              // E_DIM/4 = 256 float4, 64 lanes
        int idx = s * 64 + lane;
        float4 wv = Wi[idx], xv = x4[idx];
        acc += wv.x * xv.x + wv.y * xv.y + wv.z * xv.z + wv.w * xv.w;
    }
#pragma unroll
    for (int s = 0; s < 8; ++s) {              // H_DIM/4 = 512 float4
        int idx = s * 64 + lane;
        float4 wv = Wh[idx], hv = h4[idx];
        acc += wv.x * hv.x + wv.y * hv.y + wv.z * hv.z + wv.w * hv.w;
    }
#pragma unroll
    for (int off = 32; off > 0; off >>= 1) acc += __shfl_xor(acc, off);
    __shared__ float gl[4];
    if (lane == 0) gl[w] = acc + b_ih[j] + b_hh[j];
    __syncthreads();
    if (threadIdx.x == 0) {
        float gi = gl[0], gf = gl[1], gg = gl[2], go = gl[3];
        float c = sigf(gf) * c0[k] + sigf(gi) * tanhf(gg);
        float h = sigf(go) * tanhf(c);
        d_out[OUT_H + k] = h;
        d_out[OUT_C + k] = c;
        ws_h[k] = h;
    }
}

// ---- fused partial GEMV: blockIdx.x<49 -> logits slice, ==49 -> ro ---------
__global__ __launch_bounds__(256) void k_big_partial(const float* __restrict__ h,
    const float* __restrict__ W_out, const float* __restrict__ W_ro,
    float* __restrict__ pl, float* __restrict__ pro)
{
    __shared__ float hs[128];
    int hc = blockIdx.y;                       // 0..15, chunk of 128 h
    if (threadIdx.x < 128) hs[threadIdx.x] = h[hc * 128 + threadIdx.x];
    __syncthreads();
    if (blockIdx.x < 49) {
        int j0 = blockIdx.x * 1024 + threadIdx.x * 4;
        if (j0 >= RULES) return;
        float4 acc = {0.f, 0.f, 0.f, 0.f};
        const float* base = W_out + (size_t)hc * 128 * RULES + j0;
#pragma unroll 8
        for (int hh = 0; hh < 128; ++hh) {
            float hv = hs[hh];
            float4 wv = *(const float4*)(base + (size_t)hh * RULES);
            acc.x = fmaf(hv, wv.x, acc.x);
            acc.y = fmaf(hv, wv.y, acc.y);
            acc.z = fmaf(hv, wv.z, acc.z);
            acc.w = fmaf(hv, wv.w, acc.w);
        }
        *(float4*)(pl + (size_t)hc * RULES + j0) = acc;
    } else {
        int j0 = threadIdx.x * 4;
        float4 acc = {0.f, 0.f, 0.f, 0.f};
        const float* base = W_ro + (size_t)hc * 128 * R_DIM + j0;
#pragma unroll 8
        for (int hh = 0; hh < 128; ++hh) {
            float hv = hs[hh];
            float4 wv = *(const float4*)(base + (size_t)hh * R_DIM);
            acc.x = fmaf(hv, wv.x, acc.x);
            acc.y = fmaf(hv, wv.y, acc.y);
            acc.z = fmaf(hv, wv.z, acc.z);
            acc.w = fmaf(hv, wv.w, acc.w);
        }
        *(float4*)(pro + hc * R_DIM + j0) = acc;
    }
}

// ---- finalize: blocks 0..48 logits(+bsum), block 49 remainder_out ----------
__global__ __launch_bounds__(256) void k_final(const float* __restrict__ pl,
    const float* __restrict__ b_out, const float* __restrict__ pro,
    const float* __restrict__ b_ro, float* __restrict__ logits,
    float* __restrict__ bsum, float* __restrict__ out_ro)
{
    if (blockIdx.x < 49) {
        int j0 = blockIdx.x * 1024 + threadIdx.x * 4;
        float se = 0.f;
        if (j0 < RULES) {
            float4 s = {0.f, 0.f, 0.f, 0.f};
#pragma unroll
            for (int hc = 0; hc < 16; ++hc) {
                float4 p = *(const float4*)(pl + (size_t)hc * RULES + j0);
                s.x += p.x; s.y += p.y; s.z += p.z; s.w += p.w;
            }
            float4 b = *(const float4*)(b_out + j0);
            float4 l;
            l.x = fmaxf(s.x + b.x, 0.f);
            l.y = fmaxf(s.y + b.y, 0.f);
            l.z = fmaxf(s.z + b.z, 0.f);
            l.w = fmaxf(s.w + b.w, 0.f);
            *(float4*)(logits + j0) = l;
            se = expf(l.x) + expf(l.y) + expf(l.z) + expf(l.w);
        }
        __shared__ float red[256];
        red[threadIdx.x] = se;
        __syncthreads();
        for (int off = 128; off > 0; off >>= 1) {
            if (threadIdx.x < off) red[threadIdx.x] += red[threadIdx.x + off];
            __syncthreads();
        }
        if (threadIdx.x == 0) bsum[blockIdx.x] = red[0];
    } else {
        int j0 = threadIdx.x * 4;
        float4 s = {0.f, 0.f, 0.f, 0.f};
#pragma unroll
        for (int hc = 0; hc < 16; ++hc) {
            float4 p = *(const float4*)(pro + hc * R_DIM + j0);
            s.x += p.x; s.y += p.y; s.z += p.z; s.w += p.w;
        }
        float4 b = *(const float4*)(b_ro + j0);
        float4 o;
        o.x = fmaxf(s.x + b.x, 0.f);
        o.y = fmaxf(s.y + b.y, 0.f);
        o.z = fmaxf(s.z + b.z, 0.f);
        o.w = fmaxf(s.w + b.w, 0.f);
        *(float4*)(out_ro + j0) = o;
    }
}

// ---- out = logits - log(sum(exp)) ------------------------------------------
__global__ __launch_bounds__(256) void k_out(const float* __restrict__ logits,
    const float* __restrict__ bsum, float* __restrict__ d_out)
{
    __shared__ float lse_s;
    if (threadIdx.x == 0) {
        float s = 0.f;
        for (int i = 0; i < 49; ++i) s += bsum[i];   // fixed order: deterministic
        lse_s = logf(s);
    }
    __syncthreads();
    int j = blockIdx.x * 256 + threadIdx.x;
    if (j < RULES) d_out[j] = logits[j] - lse_s;
}

extern "C" void kernel_launch(void* const* d_in, const int* in_sizes, int n_in,
                              void* d_out, int out_size, void* d_ws, size_t ws_size,
                              hipStream_t stream)
{
    const int*   ident = (const int*)  d_in[0];
    const float* rem   = (const float*)d_in[1];
    const float* h0    = (const float*)d_in[2];
    const float* c0    = (const float*)d_in[3];
    const float* emb   = (const float*)d_in[4];
    const float* W_rin = (const float*)d_in[5];
    const float* b_rin = (const float*)d_in[6];
    const float* W_ih  = (const float*)d_in[7];
    const float* W_hh  = (const float*)d_in[8];
    const float* b_ih  = (const float*)d_in[9];
    const float* b_hh  = (const float*)d_in[10];
    const float* W_ro  = (const float*)d_in[11];
    const float* b_ro  = (const float*)d_in[12];
    const float* W_out = (const float*)d_in[13];
    const float* b_out = (const float*)d_in[14];
    float* out = (float*)d_out;
    float* ws  = (float*)d_ws;

    k_x_partial<<<dim3(4, 8), 256, 0, stream>>>(rem, W_rin, ws + WS_XP);
    k_lstm<<<2048, 256, 0, stream>>>(ws + WS_XP, b_rin, emb, ident,
                                     h0, c0, W_ih, W_hh, b_ih, b_hh,
                                     out, ws + WS_H);
    k_big_partial<<<dim3(50, 16), 256, 0, stream>>>(ws + WS_H, W_out, W_ro,
                                                    ws + WS_PL, ws + WS_PRO);
    k_final<<<50, 256, 0, stream>>>(ws + WS_PL, b_out, ws + WS_PRO, b_ro,
                                    ws + WS_LOG, ws + WS_BSUM, out + OUT_RO);
    k_out<<<196, 256, 0, stream>>>(ws + WS_LOG, ws + WS_BSUM, out);
}

// Round 3
// 110.946 us; speedup vs baseline: 1.1599x; 1.1096x over previous
//
#include <hip/hip_runtime.h>
#include <math.h>

#define E_DIM 1024
#define H_DIM 2048
#define R_DIM 1024
#define RULES 50000

// d_out layout: [out 50000][h 2048][c 2048][remainder_out 1024]
#define OUT_H  50000
#define OUT_C  52048
#define OUT_RO 54096

// ws layout (float offsets); all blocks write disjoint fixed slots -> deterministic
#define WS_XP    0          // [8][1024]    x partials (rem @ W_rin)
#define WS_H     8192       // [2048]       h
#define WS_CNT   10240      // [1]          barrier counter (re-zeroed every call)
#define WS_PL    10256      // [32][50000]  logits partials
#define WS_PRO   1610256    // [32][1024]   remainder_out partials
#define WS_BSUM  1643024    // [49]         per-block sum(exp(logit))

typedef float f32x4 __attribute__((ext_vector_type(4)));

__device__ __forceinline__ f32x4 nt4(const float* p) {
    return __builtin_nontemporal_load((const f32x4*)p);
}

__device__ __forceinline__ float sigf(float x) { return 1.f / (1.f + expf(-x)); }

// ---- xp[rc][e] = partial of rem @ W_rin; also re-zeroes barrier counter ----
__global__ __launch_bounds__(256) void k_x_partial(const float* __restrict__ rem,
    const float* __restrict__ W_rin, float* __restrict__ xp,
    unsigned int* __restrict__ cnt)
{
    if (blockIdx.x == 0 && blockIdx.y == 0 && threadIdx.x == 0) *cnt = 0u;
    __shared__ float rs[128];
    int ec = blockIdx.x, rc = blockIdx.y;
    if (threadIdx.x < 128) rs[threadIdx.x] = rem[rc * 128 + threadIdx.x];
    __syncthreads();
    int e = ec * 256 + threadIdx.x;
    const float* base = W_rin + (size_t)rc * 128 * E_DIM + e;
    float acc = 0.f;
#pragma unroll 8
    for (int rr = 0; rr < 128; ++rr)
        acc = fmaf(rs[rr], base[(size_t)rr * E_DIM], acc);
    xp[rc * E_DIM + e] = acc;
}

// ---- LSTM cell; rebuilds x per block from xp (L2-resident) -----------------
__global__ __launch_bounds__(256) void k_lstm(const float* __restrict__ xp,
    const float* __restrict__ b_rin, const float* __restrict__ emb,
    const int* __restrict__ ident,
    const float* __restrict__ h0, const float* __restrict__ c0,
    const float* __restrict__ W_ih, const float* __restrict__ W_hh,
    const float* __restrict__ b_ih, const float* __restrict__ b_hh,
    float* __restrict__ d_out, float* __restrict__ ws_h)
{
    __shared__ float xs[E_DIM];
    long long row = (long long)ident[0] * E_DIM;
#pragma unroll
    for (int e = threadIdx.x; e < E_DIM; e += 256) {
        float s = 0.f;
#pragma unroll
        for (int rc = 0; rc < 8; ++rc) s += xp[rc * E_DIM + e];
        xs[e] = emb[row + e] + fmaxf(s + b_rin[e], 0.f);
    }
    __syncthreads();

    int k = blockIdx.x;
    int w = threadIdx.x >> 6, lane = threadIdx.x & 63;
    int j = w * H_DIM + k;   // torch gate order i,f,g,o == split order
    const float* Wi = W_ih + (size_t)j * E_DIM;
    const float* Wh = W_hh + (size_t)j * H_DIM;
    const f32x4* x4 = (const f32x4*)xs;
    const f32x4* h4 = (const f32x4*)h0;
    float acc = 0.f;
#pragma unroll
    for (int s = 0; s < 4; ++s) {              // E_DIM/4 = 256 float4, 64 lanes
        int idx = s * 64 + lane;
        f32x4 wv = nt4(Wi + idx * 4);
        f32x4 xv = x4[idx];
        acc += wv.x * xv.x + wv.y * xv.y + wv.z * xv.z + wv.w * xv.w;
    }
#pragma unroll
    for (int s = 0; s < 8; ++s) {              // H_DIM/4 = 512 float4
        int idx = s * 64 + lane;
        f32x4 wv = nt4(Wh + idx * 4);
        f32x4 hv = h4[idx];
        acc += wv.x * hv.x + wv.y * hv.y + wv.z * hv.z + wv.w * hv.w;
    }
#pragma unroll
    for (int off = 32; off > 0; off >>= 1) acc += __shfl_xor(acc, off);
    __shared__ float gl[4];
    if (lane == 0) gl[w] = acc + b_ih[j] + b_hh[j];
    __syncthreads();
    if (threadIdx.x == 0) {
        float gi = gl[0], gf = gl[1], gg = gl[2], go = gl[3];
        float c = sigf(gf) * c0[k] + sigf(gi) * tanhf(gg);
        float h = sigf(go) * tanhf(c);
        d_out[OUT_H + k] = h;
        d_out[OUT_C + k] = c;
        ws_h[k] = h;
    }
}

// ---- fused partial GEMV: blockIdx.x<49 -> logits slice, ==49 -> ro ---------
// grid (50, 32): hc = chunk of 64 h-elements
__global__ __launch_bounds__(256) void k_big(const float* __restrict__ h,
    const float* __restrict__ W_out, const float* __restrict__ W_ro,
    float* __restrict__ pl, float* __restrict__ pro)
{
    __shared__ float hs[64];
    int hc = blockIdx.y;                       // 0..31
    if (threadIdx.x < 64) hs[threadIdx.x] = h[hc * 64 + threadIdx.x];
    __syncthreads();
    if (blockIdx.x < 49) {
        int j0 = blockIdx.x * 1024 + threadIdx.x * 4;
        if (j0 >= RULES) return;
        f32x4 acc = {0.f, 0.f, 0.f, 0.f};
        const float* base = W_out + (size_t)hc * 64 * RULES + j0;
#pragma unroll 16
        for (int hh = 0; hh < 64; ++hh) {
            float hv = hs[hh];
            f32x4 wv = nt4(base + (size_t)hh * RULES);
            acc.x = fmaf(hv, wv.x, acc.x);
            acc.y = fmaf(hv, wv.y, acc.y);
            acc.z = fmaf(hv, wv.z, acc.z);
            acc.w = fmaf(hv, wv.w, acc.w);
        }
        *(f32x4*)(pl + (size_t)hc * RULES + j0) = acc;
    } else {
        int j0 = threadIdx.x * 4;
        f32x4 acc = {0.f, 0.f, 0.f, 0.f};
        const float* base = W_ro + (size_t)hc * 64 * R_DIM + j0;
#pragma unroll 16
        for (int hh = 0; hh < 64; ++hh) {
            float hv = hs[hh];
            f32x4 wv = nt4(base + (size_t)hh * R_DIM);
            acc.x = fmaf(hv, wv.x, acc.x);
            acc.y = fmaf(hv, wv.y, acc.y);
            acc.z = fmaf(hv, wv.z, acc.z);
            acc.w = fmaf(hv, wv.w, acc.w);
        }
        *(f32x4*)(pro + (size_t)hc * R_DIM + j0) = acc;
    }
}

// ---- tail: blocks 0..48 logits + device-barrier + log_softmax; 49 -> ro ----
__global__ __launch_bounds__(256) void k_tail(const float* __restrict__ pl,
    const float* __restrict__ b_out, const float* __restrict__ pro,
    const float* __restrict__ b_ro, unsigned int* __restrict__ cnt,
    float* __restrict__ bsum, float* __restrict__ d_out)
{
    if (blockIdx.x == 49) {                    // remainder_out finalize
        int j0 = threadIdx.x * 4;
        f32x4 s = {0.f, 0.f, 0.f, 0.f};
#pragma unroll
        for (int hc = 0; hc < 32; ++hc) {
            f32x4 p = *(const f32x4*)(pro + (size_t)hc * R_DIM + j0);
            s.x += p.x; s.y += p.y; s.z += p.z; s.w += p.w;
        }
        const f32x4 b = *(const f32x4*)(b_ro + j0);
        f32x4 o;
        o.x = fmaxf(s.x + b.x, 0.f);
        o.y = fmaxf(s.y + b.y, 0.f);
        o.z = fmaxf(s.z + b.z, 0.f);
        o.w = fmaxf(s.w + b.w, 0.f);
        *(f32x4*)(d_out + OUT_RO + j0) = o;
        return;
    }
    int j0 = blockIdx.x * 1024 + threadIdx.x * 4;
    bool valid = j0 < RULES;
    f32x4 l = {0.f, 0.f, 0.f, 0.f};
    float se = 0.f;
    if (valid) {
        f32x4 s = {0.f, 0.f, 0.f, 0.f};
#pragma unroll
        for (int hc = 0; hc < 32; ++hc) {
            f32x4 p = *(const f32x4*)(pl + (size_t)hc * RULES + j0);
            s.x += p.x; s.y += p.y; s.z += p.z; s.w += p.w;
        }
        const f32x4 b = *(const f32x4*)(b_out + j0);
        l.x = fmaxf(s.x + b.x, 0.f);
        l.y = fmaxf(s.y + b.y, 0.f);
        l.z = fmaxf(s.z + b.z, 0.f);
        l.w = fmaxf(s.w + b.w, 0.f);
        se = expf(l.x) + expf(l.y) + expf(l.z) + expf(l.w);
    }
    __shared__ float red[256];
    red[threadIdx.x] = se;
    __syncthreads();
    for (int off = 128; off > 0; off >>= 1) {
        if (threadIdx.x < off) red[threadIdx.x] += red[threadIdx.x + off];
        __syncthreads();
    }
    __shared__ float lse_s;
    if (threadIdx.x == 0) {
        bsum[blockIdx.x] = red[0];
        __threadfence();
        __hip_atomic_fetch_add(cnt, 1u, __ATOMIC_RELEASE, __HIP_MEMORY_SCOPE_AGENT);
        // all 49 logits blocks are co-resident (49 blocks << 256 CUs): safe spin
        while (__hip_atomic_load(cnt, __ATOMIC_ACQUIRE, __HIP_MEMORY_SCOPE_AGENT) < 49u) {}
        float ssum = 0.f;
        for (int i = 0; i < 49; ++i) ssum += bsum[i];  // fixed order: deterministic
        lse_s = logf(ssum);
    }
    __syncthreads();
    if (valid) {
        f32x4 o;
        o.x = l.x - lse_s; o.y = l.y - lse_s; o.z = l.z - lse_s; o.w = l.w - lse_s;
        *(f32x4*)(d_out + j0) = o;
    }
}

extern "C" void kernel_launch(void* const* d_in, const int* in_sizes, int n_in,
                              void* d_out, int out_size, void* d_ws, size_t ws_size,
                              hipStream_t stream)
{
    const int*   ident = (const int*)  d_in[0];
    const float* rem   = (const float*)d_in[1];
    const float* h0    = (const float*)d_in[2];
    const float* c0    = (const float*)d_in[3];
    const float* emb   = (const float*)d_in[4];
    const float* W_rin = (const float*)d_in[5];
    const float* b_rin = (const float*)d_in[6];
    const float* W_ih  = (const float*)d_in[7];
    const float* W_hh  = (const float*)d_in[8];
    const float* b_ih  = (const float*)d_in[9];
    const float* b_hh  = (const float*)d_in[10];
    const float* W_ro  = (const float*)d_in[11];
    const float* b_ro  = (const float*)d_in[12];
    const float* W_out = (const float*)d_in[13];
    const float* b_out = (const float*)d_in[14];
    float* out = (float*)d_out;
    float* ws  = (float*)d_ws;
    unsigned int* cnt = (unsigned int*)(ws + WS_CNT);

    k_x_partial<<<dim3(4, 8), 256, 0, stream>>>(rem, W_rin, ws + WS_XP, cnt);
    k_lstm<<<2048, 256, 0, stream>>>(ws + WS_XP, b_rin, emb, ident,
                                     h0, c0, W_ih, W_hh, b_ih, b_hh,
                                     out, ws + WS_H);
    k_big<<<dim3(50, 32), 256, 0, stream>>>(ws + WS_H, W_out, W_ro,
                                            ws + WS_PL, ws + WS_PRO);
    k_tail<<<50, 256, 0, stream>>>(ws + WS_PL, b_out, ws + WS_PRO, b_ro,
                                   cnt, ws + WS_BSUM, out);
}